// Round 11
// baseline (189.475 us; speedup 1.0000x reference)
//
#include <hip/hip_runtime.h>

static constexpr int B_   = 8;
static constexpr int C_   = 256;
static constexpr int CQK_ = 32;
static constexpr int N_   = 4096;   // 64*64

typedef __attribute__((ext_vector_type(4)))  float f32x4;
typedef __attribute__((ext_vector_type(16))) float f32x16;
typedef __attribute__((ext_vector_type(8)))  short short8;
typedef __attribute__((ext_vector_type(2)))  unsigned int u32x2;
typedef unsigned short ushort_t;

// round-to-nearest-even fp32 -> bf16
__device__ inline unsigned short f2bf(float f) {
    unsigned u = __float_as_uint(f);
    return (unsigned short)((u + 0x7FFFu + ((u >> 16) & 1u)) >> 16);
}
__device__ inline unsigned packbf(float lo, float hi) {
    return (unsigned)f2bf(lo) | ((unsigned)f2bf(hi) << 16);
}
// packed f32->bf16 pair, single VOP3 (validated r6+)
__device__ inline unsigned cvtpk(float lo, float hi) {
    unsigned r;
    asm("v_cvt_pk_bf16_f32 %0, %1, %2" : "=v"(r) : "v"(lo), "v"(hi));
    return r;
}
// raw transcendental exp2 (input = log2-domain; Q pre-scaled by log2e)
__device__ inline float vexp2(float x) {
    float r;
    asm("v_exp_f32 %0, %1" : "=v"(r) : "v"(x));
    return r;
}
// v_permlane32_swap_b32 (validated r10)
__device__ inline void plswap(unsigned& a, unsigned& b) {
    asm("v_permlane32_swap_b32 %0, %1" : "+v"(a), "+v"(b));
}

// proj x-tile swizzle (validated r3-r10)
__device__ inline int swzbits(int m) {
    return ((m & 3) << 5) | (((m >> 3) & 1) << 4);
}

template <int OFF>
__device__ inline u32x2 tr8(unsigned a) {
    u32x2 d;
    asm volatile("ds_read_b64_tr_b16 %0, %1 offset:%2"
                 : "=v"(d) : "v"(a), "i"(OFF));
    return d;
}

__device__ inline short8 mk8(u32x2 lo, u32x2 hi) {
    union { unsigned u[4]; short8 s; } v;
    v.u[0] = lo.x; v.u[1] = lo.y; v.u[2] = hi.x; v.u[3] = hi.y;
    return v.s;
}
__device__ inline short8 mk8u(unsigned a, unsigned b, unsigned c, unsigned d) {
    union { unsigned u[4]; short8 s; } v;
    v.u[0] = a; v.u[1] = b; v.u[2] = c; v.u[3] = d;
    return v.s;
}

// ---------------------------------------------------------------------------
// prep: weights -> bf16 (Wq pre-scaled by log2e), biases -> f32
// ---------------------------------------------------------------------------
__global__ __launch_bounds__(256) void prep_kernel(
    const float* __restrict__ Wq, const float* __restrict__ bq,
    const float* __restrict__ Wk, const float* __restrict__ bk,
    const float* __restrict__ Wv, const float* __restrict__ bv,
    ushort_t* __restrict__ Wall, float* __restrict__ ball)
{
    const int r = blockIdx.x;
    const int t = threadIdx.x;
    const float LOG2E = 1.4426950408889634f;
    const float* src;
    float bsrc, sc;
    if (r < 32)      { src = Wq + (size_t)r * C_;        bsrc = bq[r];      sc = LOG2E; }
    else if (r < 64) { src = Wk + (size_t)(r - 32) * C_; bsrc = bk[r - 32]; sc = 1.0f; }
    else             { src = Wv + (size_t)(r - 64) * C_; bsrc = bv[r - 64]; sc = 1.0f; }
    Wall[(size_t)r * C_ + t] = f2bf(src[t] * sc);
    if (t == 0) ball[r] = bsrc * sc;
}

// ---------------------------------------------------------------------------
// Projection via MFMA (r8-validated, incl. the 32-m-chunk V image:
//   byte = (b*128 + m/32)*16384 + c*64 + ((2*(m&31)) ^ (((c>>1)&3)<<4)) )
// grid = 512 blocks (b = blk&7, XCD-affine), 256 threads (4 waves)
// ---------------------------------------------------------------------------
__global__ __launch_bounds__(256) void proj_kernel(
    const float* __restrict__ x,
    const ushort_t* __restrict__ Wall, const float* __restrict__ ball,
    ushort_t* __restrict__ Qb, ushort_t* __restrict__ Kb, ushort_t* __restrict__ Vt)
{
    __shared__ __align__(16) unsigned char xs[C_ * 128];   // 32 KB: [c][64n] bf16
    typedef __attribute__((address_space(3))) unsigned char lds_byte;
    const unsigned sbase = (unsigned)(size_t)(lds_byte*)xs;

    const int b  = blockIdx.x & 7;
    const int n0 = (blockIdx.x >> 3) << 6;
    const int t  = threadIdx.x;

    {
        const int cst = t >> 4;
        const int n4  = (t & 15) << 2;
        const float* xb = x + (size_t)b * C_ * N_ + n0;
        #pragma unroll
        for (int i = 0; i < 16; ++i) {
            const int c = 16 * i + cst;
            float4 v = *(const float4*)(xb + (size_t)c * N_ + n4);
            u32x2 pk;
            pk.x = packbf(v.x, v.y);
            pk.y = packbf(v.z, v.w);
            *(u32x2*)(xs + c * 128 + ((n4 * 2) ^ swzbits(c))) = pk;
        }
    }
    __syncthreads();

    const int l  = t & 63, w = t >> 6;
    const int li = l & 15, g = l >> 4;
    const int rr = li >> 2, ss = l & 3;
    const int swz_tr = (rr << 5) | ((g & 1) << 4);

    f32x4 acc[5][4];
    #pragma unroll
    for (int i = 0; i < 5; ++i)
        #pragma unroll
        for (int j = 0; j < 4; ++j) acc[i][j] = (f32x4){0.f, 0.f, 0.f, 0.f};

    #pragma unroll 2
    for (int kg = 0; kg < 8; ++kg) {
        u32x2 pb[4][2];
        #pragma unroll
        for (int jn = 0; jn < 4; ++jn) {
            unsigned a = sbase + (32 * kg + 8 * g + rr) * 128
                       + ((32 * jn + 8 * ss) ^ swz_tr);
            pb[jn][0] = tr8<0>(a);
            pb[jn][1] = tr8<512>(a);
        }
        short8 af[5];
        #pragma unroll
        for (int tm = 0; tm < 5; ++tm)
            af[tm] = *(const short8*)(Wall + (size_t)(16 * (4 * tm + w) + li) * C_
                                      + 32 * kg + 8 * g);
        asm volatile("s_waitcnt lgkmcnt(0)" ::: "memory");
        __builtin_amdgcn_sched_barrier(0);
        #pragma unroll
        for (int jn = 0; jn < 4; ++jn) {
            short8 Bf = mk8(pb[jn][0], pb[jn][1]);
            acc[0][jn] = __builtin_amdgcn_mfma_f32_16x16x32_bf16(
                             af[0], Bf, acc[0][jn], 0, 0, 0);
            #pragma unroll
            for (int tm = 1; tm < 5; ++tm)
                acc[tm][jn] = __builtin_amdgcn_mfma_f32_16x16x32_bf16(
                                  Bf, af[tm], acc[tm][jn], 0, 0, 0);
        }
    }

    // ---- epilogue ----
    {
        const int oc0 = 16 * w + 4 * g;
        float4 bias = *(const float4*)(ball + oc0);
        ushort_t* dst = (w < 2) ? Qb : Kb;
        const int col = (w < 2) ? oc0 : (oc0 - 32);
        #pragma unroll
        for (int jn = 0; jn < 4; ++jn) {
            const int n = n0 + 16 * jn + li;
            f32x4 a = acc[0][jn];
            u32x2 pk;
            pk.x = packbf(a[0] + bias.x, a[1] + bias.y);
            pk.y = packbf(a[2] + bias.z, a[3] + bias.w);
            *(u32x2*)(dst + (size_t)(b * N_ + n) * CQK_ + col) = pk;
        }
    }
    // V: lane holds (n = n0+16jn+4g+r, c = 16(4tm+w)+li-64) -> 32-m image
    #pragma unroll
    for (int tm = 1; tm < 5; ++tm) {
        const int c  = 16 * (4 * tm + w) + li - 64;
        const float bc = ball[64 + c];
        const int sxc = ((c >> 1) & 3) << 4;
        #pragma unroll
        for (int jn = 0; jn < 4; ++jn) {
            const int ch = (n0 >> 5) + (jn >> 1);          // 32-m chunk index
            const int mcol = 32 * (jn & 1) + 8 * g;        // byte col 2*(m&31)
            f32x4 a = acc[tm][jn];
            u32x2 pk;
            pk.x = packbf(a[0] + bc, a[1] + bc);
            pk.y = packbf(a[2] + bc, a[3] + bc);
            char* dst = (char*)Vt + (size_t)(b * 128 + ch) * 16384
                      + c * 64 + (mcol ^ sxc);
            *(u32x2*)dst = pk;
        }
    }
}

// ---------------------------------------------------------------------------
// Fused attention, barrier-free, 32x32 tiles, in-register P, 32-q tiles.
// grid = 1024 blocks (b = blk&7), 256 threads (4 waves: 32q x 64c each).
// Per 32-m chunk: QK 2x mfma_32x32x16(K,Q); exp; cvtpk+permlane -> PV
// A-frags in registers; PV 4x mfma from wave-private dbuf'd 4KB V quarter.
// LDS: 4 waves * 2 * 4KB + 4*128B rowsum = 33280 B -> 4 blocks/CU.
// ---------------------------------------------------------------------------
__global__ __launch_bounds__(256) void attn_kernel(
    const float* __restrict__ x,
    const ushort_t* __restrict__ Qb, const ushort_t* __restrict__ Kb,
    const ushort_t* __restrict__ Vt,
    const float* __restrict__ gamma, float* __restrict__ out)
{
    __shared__ __align__(16) unsigned char smem[33280];

    const int b   = blockIdx.x & 7;
    const int n0  = (blockIdx.x >> 3) << 5;          // 32-q tile
    const int t   = threadIdx.x;
    const int l   = t & 63, w = t >> 6;
    const int l31 = l & 31, h2 = l >> 5;
    const int sxv = ((l31 >> 1) & 3) << 4;           // matches V image swizzle
    unsigned char* wlds = smem + w * 8192;           // 2 x 4 KB private V bufs
    float* rslw = (float*)(smem + 32768) + w * 32;   // wave-private rowsums

    // Q fragments (B-role: col = l31 -> q = n0+l31; k = 16kh+8h2+j)
    short8 qfv[2];
    #pragma unroll
    for (int kh = 0; kh < 2; ++kh)
        qfv[kh] = *(const short8*)(Qb
            + (size_t)(b * N_ + n0 + l31) * CQK_ + 16 * kh + 8 * h2);

    f32x16 acc[2];
    #pragma unroll
    for (int j = 0; j < 2; ++j)
        #pragma unroll
        for (int e = 0; e < 16; ++e) acc[j][e] = 0.f;
    f32x16 zf16;
    #pragma unroll
    for (int e = 0; e < 16; ++e) zf16[e] = 0.f;
    float rs = 0.f;

    const ushort_t* Kbb = Kb + (size_t)(b * N_) * CQK_;
    const char* Vgb = (const char*)Vt + (size_t)b * 128 * 16384 + w * 4096;

    short8 kfA[2], kfB[2];

    // ---- prologue: K(0) -> kfA, DMA(0) -> buf0 (own c-quarter) ----
    #pragma unroll
    for (int kh = 0; kh < 2; ++kh)
        kfA[kh] = *(const short8*)(Kbb + (size_t)l31 * CQK_ + 16 * kh + 8 * h2);
    #pragma unroll
    for (int i = 0; i < 4; ++i)
        __builtin_amdgcn_global_load_lds(
            (const __attribute__((address_space(1))) unsigned int*)(Vgb + l * 16 + i * 1024),
            (__attribute__((address_space(3))) unsigned int*)(wlds + l * 16 + i * 1024),
            16, 0, 0);

#define CHUNK_BODY(CH, KFC, KFN)                                                \
    {                                                                           \
        const int chn = ((CH) + 1) & 127;                                       \
        /* 1. K(n+1) -> regs */                                                 \
        _Pragma("unroll")                                                       \
        for (int kh = 0; kh < 2; ++kh)                                          \
            KFN[kh] = *(const short8*)(Kbb                                      \
                + (size_t)(32 * chn + l31) * CQK_ + 16 * kh + 8 * h2);          \
        /* 2. DMA(n+1) own c-quarter -> other buffer */                         \
        {                                                                       \
            const char* gsrc = Vgb + (size_t)chn * 16384 + l * 16;              \
            unsigned char* ldst = wlds + (((CH) + 1) & 1) * 4096 + l * 16;      \
            _Pragma("unroll")                                                   \
            for (int i = 0; i < 4; ++i)                                         \
                __builtin_amdgcn_global_load_lds(                               \
                    (const __attribute__((address_space(1))) unsigned int*)(gsrc + i * 1024), \
                    (__attribute__((address_space(3))) unsigned int*)(ldst + i * 1024), \
                    16, 0, 0);                                                  \
        }                                                                       \
        /* 3. QK (32x32, K=32 via 2 mfma), exp, pack, permlane -> A-frags */    \
        unsigned paw[2][4];                                                     \
        {                                                                       \
            f32x16 sv = __builtin_amdgcn_mfma_f32_32x32x16_bf16(                \
                            KFC[0], qfv[0], zf16, 0, 0, 0);                     \
            sv = __builtin_amdgcn_mfma_f32_32x32x16_bf16(                       \
                     KFC[1], qfv[1], sv, 0, 0, 0);                              \
            float ev[16];                                                       \
            _Pragma("unroll")                                                   \
            for (int e = 0; e < 16; ++e) ev[e] = vexp2(sv[e]);                  \
            rs += (((ev[0] + ev[1]) + (ev[2] + ev[3]))                          \
                 + ((ev[4] + ev[5]) + (ev[6] + ev[7])))                         \
                + (((ev[8] + ev[9]) + (ev[10] + ev[11]))                        \
                 + ((ev[12] + ev[13]) + (ev[14] + ev[15])));                    \
            unsigned u0 = cvtpk(ev[0], ev[1]),   u1 = cvtpk(ev[2], ev[3]);      \
            unsigned u2 = cvtpk(ev[4], ev[5]),   u3 = cvtpk(ev[6], ev[7]);      \
            unsigned u4 = cvtpk(ev[8], ev[9]),   u5 = cvtpk(ev[10], ev[11]);    \
            unsigned u6 = cvtpk(ev[12], ev[13]), u7 = cvtpk(ev[14], ev[15]);    \
            plswap(u0, u2); plswap(u1, u3);                                     \
            plswap(u4, u6); plswap(u5, u7);                                     \
            paw[0][0] = u0; paw[0][1] = u1; paw[0][2] = u2; paw[0][3] = u3;     \
            paw[1][0] = u4; paw[1][1] = u5; paw[1][2] = u6; paw[1][3] = u7;     \
        }                                                                       \
        /* 4. my DMA(n) retired; K(n+1)=2 + DMA(n+1)=4 stay in flight */        \
        asm volatile("s_waitcnt vmcnt(6)" ::: "memory");                        \
        /* 5. PV: A = register P, B = V b128 (own quarter) */                   \
        {                                                                       \
            const unsigned char* vb = wlds + ((CH) & 1) * 4096;                 \
            short8 vv[2][2];                                                    \
            _Pragma("unroll")                                                   \
            for (int jc = 0; jc < 2; ++jc)                                      \
                _Pragma("unroll")                                               \
                for (int s = 0; s < 2; ++s)                                     \
                    vv[jc][s] = *(const short8*)(vb + (32 * jc + l31) * 64      \
                                   + ((32 * s + 16 * h2) ^ sxv));               \
            _Pragma("unroll")                                                   \
            for (int jc = 0; jc < 2; ++jc)                                      \
                _Pragma("unroll")                                               \
                for (int s = 0; s < 2; ++s)                                     \
                    acc[jc] = __builtin_amdgcn_mfma_f32_32x32x16_bf16(          \
                        mk8u(paw[s][0], paw[s][1], paw[s][2], paw[s][3]),       \
                        vv[jc][s], acc[jc], 0, 0, 0);                           \
        }                                                                       \
    }

    for (int mc = 0; mc < 128; mc += 2) {
        CHUNK_BODY(mc,     kfA, kfB)
        CHUNK_BODY(mc + 1, kfB, kfA)
    }
#undef CHUNK_BODY

    // ---- rowsum (q = l31): halves hold complementary m-sets ----
    rs += __shfl_xor(rs, 32, 64);
    if (l < 32) rslw[l31] = rs;
    asm volatile("s_waitcnt lgkmcnt(0)" ::: "memory");

    // ---- epilogue: out = gamma * acc / rowsum + x ----
    const float gm = gamma[0];
    #pragma unroll
    for (int rg = 0; rg < 4; ++rg) {
        f32x4 sv = *(const f32x4*)(rslw + 8 * rg + 4 * h2);
        float i0 = 1.0f / sv[0], i1 = 1.0f / sv[1];
        float i2 = 1.0f / sv[2], i3 = 1.0f / sv[3];
        const int n = n0 + 8 * rg + 4 * h2;
        #pragma unroll
        for (int jc = 0; jc < 2; ++jc) {
            const int c = 64 * w + 32 * jc + l31;
            const size_t rowoff = (size_t)(b * C_ + c) * N_ + n;
            float4 xv = *(const float4*)(x + rowoff);
            float4 o;
            o.x = gm * acc[jc][4 * rg + 0] * i0 + xv.x;
            o.y = gm * acc[jc][4 * rg + 1] * i1 + xv.y;
            o.z = gm * acc[jc][4 * rg + 2] * i2 + xv.z;
            o.w = gm * acc[jc][4 * rg + 3] * i3 + xv.w;
            *(float4*)(out + rowoff) = o;
        }
    }
}

// ---------------------------------------------------------------------------
extern "C" void kernel_launch(void* const* d_in, const int* in_sizes, int n_in,
                              void* d_out, int out_size, void* d_ws, size_t ws_size,
                              hipStream_t stream)
{
    const float* x     = (const float*)d_in[0];
    const float* Wq    = (const float*)d_in[1];
    const float* bq    = (const float*)d_in[2];
    const float* Wk    = (const float*)d_in[3];
    const float* bk    = (const float*)d_in[4];
    const float* Wv    = (const float*)d_in[5];
    const float* bv    = (const float*)d_in[6];
    const float* gamma = (const float*)d_in[7];
    float* out = (float*)d_out;

    ushort_t* ws = (ushort_t*)d_ws;
    ushort_t* Qb   = ws;                                  // B*N*32 bf16
    ushort_t* Kb   = Qb + (size_t)B_ * N_ * CQK_;         // B*N*32 bf16
    ushort_t* Vt   = Kb + (size_t)B_ * N_ * CQK_;         // B*128 chunks * 16KB
    ushort_t* Wall = Vt + (size_t)B_ * C_ * N_;           // 320*256 bf16
    float*    ball = (float*)(Wall + (size_t)320 * C_);   // 320 f32

    prep_kernel<<<320, 256, 0, stream>>>(Wq, bq, Wk, bk, Wv, bv, Wall, ball);
    proj_kernel<<<B_ * (N_ / 64), 256, 0, stream>>>(x, Wall, ball, Qb, Kb, Vt);
    attn_kernel<<<B_ * (N_ / 32), 256, 0, stream>>>(x, Qb, Kb, Vt, gamma, out);
}

// Round 12
// 137.977 us; speedup vs baseline: 1.3732x; 1.3732x over previous
//
#include <hip/hip_runtime.h>

static constexpr int B_   = 8;
static constexpr int C_   = 256;
static constexpr int CQK_ = 32;
static constexpr int N_   = 4096;   // 64*64

typedef __attribute__((ext_vector_type(4)))  float f32x4;
typedef __attribute__((ext_vector_type(16))) float f32x16;
typedef __attribute__((ext_vector_type(8)))  short short8;
typedef __attribute__((ext_vector_type(2)))  unsigned int u32x2;
typedef unsigned short ushort_t;

// round-to-nearest-even fp32 -> bf16
__device__ inline unsigned short f2bf(float f) {
    unsigned u = __float_as_uint(f);
    return (unsigned short)((u + 0x7FFFu + ((u >> 16) & 1u)) >> 16);
}
__device__ inline unsigned packbf(float lo, float hi) {
    return (unsigned)f2bf(lo) | ((unsigned)f2bf(hi) << 16);
}
// packed f32->bf16 pair, single VOP3 (validated r6+)
__device__ inline unsigned cvtpk(float lo, float hi) {
    unsigned r;
    asm("v_cvt_pk_bf16_f32 %0, %1, %2" : "=v"(r) : "v"(lo), "v"(hi));
    return r;
}
// raw transcendental exp2 (input = log2-domain; Q pre-scaled by log2e)
__device__ inline float vexp2(float x) {
    float r;
    asm("v_exp_f32 %0, %1" : "=v"(r) : "v"(x));
    return r;
}
// v_permlane32_swap_b32 (validated r10)
__device__ inline void plswap(unsigned& a, unsigned& b) {
    asm("v_permlane32_swap_b32 %0, %1" : "+v"(a), "+v"(b));
}

// proj x-tile swizzle (validated r3-r11)
__device__ inline int swzbits(int m) {
    return ((m & 3) << 5) | (((m >> 3) & 1) << 4);
}

template <int OFF>
__device__ inline u32x2 tr8(unsigned a) {
    u32x2 d;
    asm volatile("ds_read_b64_tr_b16 %0, %1 offset:%2"
                 : "=v"(d) : "v"(a), "i"(OFF));
    return d;
}

__device__ inline short8 mk8(u32x2 lo, u32x2 hi) {
    union { unsigned u[4]; short8 s; } v;
    v.u[0] = lo.x; v.u[1] = lo.y; v.u[2] = hi.x; v.u[3] = hi.y;
    return v.s;
}
__device__ inline short8 mk8u(unsigned a, unsigned b, unsigned c, unsigned d) {
    union { unsigned u[4]; short8 s; } v;
    v.u[0] = a; v.u[1] = b; v.u[2] = c; v.u[3] = d;
    return v.s;
}

// ---------------------------------------------------------------------------
// prep: weights -> bf16 (Wq pre-scaled by log2e), biases -> f32
// ---------------------------------------------------------------------------
__global__ __launch_bounds__(256) void prep_kernel(
    const float* __restrict__ Wq, const float* __restrict__ bq,
    const float* __restrict__ Wk, const float* __restrict__ bk,
    const float* __restrict__ Wv, const float* __restrict__ bv,
    ushort_t* __restrict__ Wall, float* __restrict__ ball)
{
    const int r = blockIdx.x;
    const int t = threadIdx.x;
    const float LOG2E = 1.4426950408889634f;
    const float* src;
    float bsrc, sc;
    if (r < 32)      { src = Wq + (size_t)r * C_;        bsrc = bq[r];      sc = LOG2E; }
    else if (r < 64) { src = Wk + (size_t)(r - 32) * C_; bsrc = bk[r - 32]; sc = 1.0f; }
    else             { src = Wv + (size_t)(r - 64) * C_; bsrc = bv[r - 64]; sc = 1.0f; }
    Wall[(size_t)r * C_ + t] = f2bf(src[t] * sc);
    if (t == 0) ball[r] = bsrc * sc;
}

// ---------------------------------------------------------------------------
// Projection via MFMA. Q/K as r5-r10. V -> QUADRANT image per 64-m chunk:
//   quadrant (ch = c>>7, mh = (m&63)>>5), 8KB block:
//   byte = ((b*64+chunk)*4 + 2*ch + mh)*8192 + (c&127)*64
//        + 16*(((m&31)>>3) ^ (c&3) ^ ((c>>2)&3)) + 2*(m&7)
// grid = 512 blocks (b = blk&7, XCD-affine), 256 threads (4 waves)
// ---------------------------------------------------------------------------
__global__ __launch_bounds__(256) void proj_kernel(
    const float* __restrict__ x,
    const ushort_t* __restrict__ Wall, const float* __restrict__ ball,
    ushort_t* __restrict__ Qb, ushort_t* __restrict__ Kb, ushort_t* __restrict__ Vt)
{
    __shared__ __align__(16) unsigned char xs[C_ * 128];   // 32 KB: [c][64n] bf16
    typedef __attribute__((address_space(3))) unsigned char lds_byte;
    const unsigned sbase = (unsigned)(size_t)(lds_byte*)xs;

    const int b  = blockIdx.x & 7;
    const int n0 = (blockIdx.x >> 3) << 6;
    const int t  = threadIdx.x;

    {
        const int cst = t >> 4;
        const int n4  = (t & 15) << 2;
        const float* xb = x + (size_t)b * C_ * N_ + n0;
        #pragma unroll
        for (int i = 0; i < 16; ++i) {
            const int c = 16 * i + cst;
            float4 v = *(const float4*)(xb + (size_t)c * N_ + n4);
            u32x2 pk;
            pk.x = packbf(v.x, v.y);
            pk.y = packbf(v.z, v.w);
            *(u32x2*)(xs + c * 128 + ((n4 * 2) ^ swzbits(c))) = pk;
        }
    }
    __syncthreads();

    const int l  = t & 63, w = t >> 6;
    const int li = l & 15, g = l >> 4;
    const int rr = li >> 2, ss = l & 3;
    const int swz_tr = (rr << 5) | ((g & 1) << 4);

    f32x4 acc[5][4];
    #pragma unroll
    for (int i = 0; i < 5; ++i)
        #pragma unroll
        for (int j = 0; j < 4; ++j) acc[i][j] = (f32x4){0.f, 0.f, 0.f, 0.f};

    #pragma unroll 2
    for (int kg = 0; kg < 8; ++kg) {
        u32x2 pb[4][2];
        #pragma unroll
        for (int jn = 0; jn < 4; ++jn) {
            unsigned a = sbase + (32 * kg + 8 * g + rr) * 128
                       + ((32 * jn + 8 * ss) ^ swz_tr);
            pb[jn][0] = tr8<0>(a);
            pb[jn][1] = tr8<512>(a);
        }
        short8 af[5];
        #pragma unroll
        for (int tm = 0; tm < 5; ++tm)
            af[tm] = *(const short8*)(Wall + (size_t)(16 * (4 * tm + w) + li) * C_
                                      + 32 * kg + 8 * g);
        asm volatile("s_waitcnt lgkmcnt(0)" ::: "memory");
        __builtin_amdgcn_sched_barrier(0);
        #pragma unroll
        for (int jn = 0; jn < 4; ++jn) {
            short8 Bf = mk8(pb[jn][0], pb[jn][1]);
            acc[0][jn] = __builtin_amdgcn_mfma_f32_16x16x32_bf16(
                             af[0], Bf, acc[0][jn], 0, 0, 0);
            #pragma unroll
            for (int tm = 1; tm < 5; ++tm)
                acc[tm][jn] = __builtin_amdgcn_mfma_f32_16x16x32_bf16(
                                  Bf, af[tm], acc[tm][jn], 0, 0, 0);
        }
    }

    // ---- epilogue: Q/K (unchanged, validated) ----
    {
        const int oc0 = 16 * w + 4 * g;
        float4 bias = *(const float4*)(ball + oc0);
        ushort_t* dst = (w < 2) ? Qb : Kb;
        const int col = (w < 2) ? oc0 : (oc0 - 32);
        #pragma unroll
        for (int jn = 0; jn < 4; ++jn) {
            const int n = n0 + 16 * jn + li;
            f32x4 a = acc[0][jn];
            u32x2 pk;
            pk.x = packbf(a[0] + bias.x, a[1] + bias.y);
            pk.y = packbf(a[2] + bias.z, a[3] + bias.w);
            *(u32x2*)(dst + (size_t)(b * N_ + n) * CQK_ + col) = pk;
        }
    }
    // ---- epilogue: V quadrant image ----
    // lane holds (m' = 16jn+4g+r within 64-chunk, c = 16(4tm+w)+li-64)
    #pragma unroll
    for (int tm = 1; tm < 5; ++tm) {
        const int c  = 16 * (4 * tm + w) + li - 64;
        const float bc = ball[64 + c];
        const int ch = c >> 7;
        const int cl = c & 127;
        const int X  = (c & 3) ^ ((c >> 2) & 3);
        char* qbase = (char*)Vt + ((size_t)(b * 64 + (n0 >> 6)) * 4 + 2 * ch) * 8192
                    + cl * 64;
        #pragma unroll
        for (int jn = 0; jn < 4; ++jn) {
            const int mp = 16 * jn + 4 * g;        // m' base (r=0..3 packed)
            const int mh = mp >> 5;
            const int jg = (mp & 31) >> 3;         // m-granule within half
            f32x4 a = acc[tm][jn];
            u32x2 pk;
            pk.x = packbf(a[0] + bc, a[1] + bc);
            pk.y = packbf(a[2] + bc, a[3] + bc);
            *(u32x2*)(qbase + mh * 8192 + 16 * (jg ^ X) + 8 * (g & 1)) = pk;
        }
    }
}

// ---------------------------------------------------------------------------
// Fused attention: quadrant split, barrier-free main loop, in-register P.
// Wave w: m-half mh=w&1, c-half ch=w>>1. Per 64-m chunk: QK for own m-half
// (2 mfma_32x32x16), 32 exp, cvtpk+permlane -> A-frags in regs; PV 16 mfma
// over 128c from wave-private dbuf'd 8KB V quadrant (linear DMA). End:
// cross-wave combine of partial acc + rowsums (2 syncthreads total).
// LDS: 4 waves * 2 * 8KB + 1KB rstab = 66560 B -> 2 blocks/CU.
// ---------------------------------------------------------------------------
__global__ __launch_bounds__(256, 2) void attn_kernel(
    const float* __restrict__ x,
    const ushort_t* __restrict__ Qb, const ushort_t* __restrict__ Kb,
    const ushort_t* __restrict__ Vt,
    const float* __restrict__ gamma, float* __restrict__ out)
{
    __shared__ __align__(16) unsigned char smem[66560];

    const int b   = blockIdx.x & 7;
    const int n0  = (blockIdx.x >> 3) << 6;
    const int t   = threadIdx.x;
    const int l   = t & 63, w = t >> 6;
    const int l31 = l & 31, h2 = l >> 5;
    const int mh  = w & 1,  ch = w >> 1;
    const int sxv = ((l31 & 3) ^ ((l31 >> 2) & 3)) << 4;   // V read swizzle
    unsigned char* wlds = smem + w * 16384;        // 2 x 8 KB private V bufs
    float* rstab = (float*)(smem + 65536);         // [w][jq][32] partial rowsums

    // Q fragments (B-role: col = l31 -> q = n0+32jq+l31; k = 16kh+8h2+j)
    short8 qfv[2][2];
    #pragma unroll
    for (int jq = 0; jq < 2; ++jq)
        #pragma unroll
        for (int kh = 0; kh < 2; ++kh)
            qfv[jq][kh] = *(const short8*)(Qb
                + (size_t)(b * N_ + n0 + 32 * jq + l31) * CQK_ + 16 * kh + 8 * h2);

    f32x16 acc[2][4];
    #pragma unroll
    for (int i = 0; i < 2; ++i)
        #pragma unroll
        for (int j = 0; j < 4; ++j)
            #pragma unroll
            for (int e = 0; e < 16; ++e) acc[i][j][e] = 0.f;
    f32x16 zf16;
    #pragma unroll
    for (int e = 0; e < 16; ++e) zf16[e] = 0.f;
    float rs[2] = {0.f, 0.f};

    const ushort_t* Kbb = Kb + (size_t)(b * N_) * CQK_;
    const char* Vgb = (const char*)Vt + (size_t)b * 64 * 32768
                    + (2 * ch + mh) * 8192;        // my quadrant base

    short8 kfA[2], kfB[2];

    // ---- prologue: K(0) own m-half -> kfA, DMA(0) quadrant -> buf0 ----
    #pragma unroll
    for (int kh = 0; kh < 2; ++kh)
        kfA[kh] = *(const short8*)(Kbb + (size_t)(32 * mh + l31) * CQK_
                                   + 16 * kh + 8 * h2);
    #pragma unroll
    for (int i = 0; i < 8; ++i)
        __builtin_amdgcn_global_load_lds(
            (const __attribute__((address_space(1))) unsigned int*)(Vgb + l * 16 + i * 1024),
            (__attribute__((address_space(3))) unsigned int*)(wlds + l * 16 + i * 1024),
            16, 0, 0);

#define CHUNK_BODY(CH, KFC, KFN)                                                \
    {                                                                           \
        const int chn = ((CH) + 1) & 63;                                        \
        /* 1. K(n+1) own m-half -> regs */                                      \
        _Pragma("unroll")                                                       \
        for (int kh = 0; kh < 2; ++kh)                                          \
            KFN[kh] = *(const short8*)(Kbb                                      \
                + (size_t)(64 * chn + 32 * mh + l31) * CQK_ + 16 * kh + 8 * h2);\
        /* 2. DMA(n+1) own quadrant -> other buffer (linear copy) */            \
        {                                                                       \
            const char* gsrc = Vgb + (size_t)chn * 32768 + l * 16;              \
            unsigned char* ldst = wlds + (((CH) + 1) & 1) * 8192 + l * 16;      \
            _Pragma("unroll")                                                   \
            for (int i = 0; i < 8; ++i)                                         \
                __builtin_amdgcn_global_load_lds(                               \
                    (const __attribute__((address_space(1))) unsigned int*)(gsrc + i * 1024), \
                    (__attribute__((address_space(3))) unsigned int*)(ldst + i * 1024), \
                    16, 0, 0);                                                  \
        }                                                                       \
        /* 3. QK (own 32-m half), exp, pack, permlane -> A-frags */             \
        unsigned paw[2][2][4];                                                  \
        _Pragma("unroll")                                                       \
        for (int jq = 0; jq < 2; ++jq) {                                        \
            f32x16 sv = __builtin_amdgcn_mfma_f32_32x32x16_bf16(                \
                            KFC[0], qfv[jq][0], zf16, 0, 0, 0);                 \
            sv = __builtin_amdgcn_mfma_f32_32x32x16_bf16(                       \
                     KFC[1], qfv[jq][1], sv, 0, 0, 0);                          \
            float ev[16];                                                       \
            _Pragma("unroll")                                                   \
            for (int e = 0; e < 16; ++e) ev[e] = vexp2(sv[e]);                  \
            rs[jq] += (((ev[0] + ev[1]) + (ev[2] + ev[3]))                      \
                     + ((ev[4] + ev[5]) + (ev[6] + ev[7])))                     \
                    + (((ev[8] + ev[9]) + (ev[10] + ev[11]))                    \
                     + ((ev[12] + ev[13]) + (ev[14] + ev[15])));                \
            unsigned u0 = cvtpk(ev[0], ev[1]),   u1 = cvtpk(ev[2], ev[3]);      \
            unsigned u2 = cvtpk(ev[4], ev[5]),   u3 = cvtpk(ev[6], ev[7]);      \
            unsigned u4 = cvtpk(ev[8], ev[9]),   u5 = cvtpk(ev[10], ev[11]);    \
            unsigned u6 = cvtpk(ev[12], ev[13]), u7 = cvtpk(ev[14], ev[15]);    \
            plswap(u0, u2); plswap(u1, u3);                                     \
            plswap(u4, u6); plswap(u5, u7);                                     \
            paw[jq][0][0] = u0; paw[jq][0][1] = u1;                             \
            paw[jq][0][2] = u2; paw[jq][0][3] = u3;                             \
            paw[jq][1][0] = u4; paw[jq][1][1] = u5;                             \
            paw[jq][1][2] = u6; paw[jq][1][3] = u7;                             \
        }                                                                       \
        /* 4. my DMA(n) retired; K(n+1)=2 + DMA(n+1)=8 stay in flight */        \
        asm volatile("s_waitcnt vmcnt(10)" ::: "memory");                       \
        /* 5. PV: A = register P (k = own m-half), B = V quadrant b128 */       \
        {                                                                       \
            const unsigned char* vb = wlds + ((CH) & 1) * 8192;                 \
            _Pragma("unroll")                                                   \
            for (int s = 0; s < 2; ++s) {                                       \
                short8 vv[4];                                                   \
                _Pragma("unroll")                                               \
                for (int jc = 0; jc < 4; ++jc)                                  \
                    vv[jc] = *(const short8*)(vb + (32 * jc + l31) * 64         \
                                   + ((32 * s + 16 * h2) ^ sxv));               \
                _Pragma("unroll")                                               \
                for (int jq = 0; jq < 2; ++jq) {                                \
                    short8 A = mk8u(paw[jq][s][0], paw[jq][s][1],               \
                                    paw[jq][s][2], paw[jq][s][3]);              \
                    _Pragma("unroll")                                           \
                    for (int jc = 0; jc < 4; ++jc)                              \
                        acc[jq][jc] = __builtin_amdgcn_mfma_f32_32x32x16_bf16(  \
                                          A, vv[jc], acc[jq][jc], 0, 0, 0);     \
                }                                                               \
            }                                                                   \
        }                                                                       \
    }

    for (int mc = 0; mc < 64; mc += 2) {
        CHUNK_BODY(mc,     kfA, kfB)
        CHUNK_BODY(mc + 1, kfB, kfA)
    }
#undef CHUNK_BODY

    // ---- partial rowsums (own m-half): combine h2 halves, publish ----
    #pragma unroll
    for (int jq = 0; jq < 2; ++jq)
        rs[jq] += __shfl_xor(rs[jq], 32, 64);
    if (l < 32) {
        rstab[(w * 2 + 0) * 32 + l31] = rs[0];
        rstab[(w * 2 + 1) * 32 + l31] = rs[1];
    }
    asm volatile("s_waitcnt vmcnt(0)" ::: "memory");  // drain wrap-around DMA
    __syncthreads();

    // ---- odd waves (mh=1): write partial acc into V-buffer area ----
    if (mh == 1) {
        float* dst = (float*)(smem + ch * 32768);
        #pragma unroll
        for (int jq = 0; jq < 2; ++jq)
            #pragma unroll
            for (int jc = 0; jc < 4; ++jc) {
                float* tb = dst + (jq * 4 + jc) * 1024 + l * 16;
                #pragma unroll
                for (int e4 = 0; e4 < 4; ++e4) {
                    f32x4 p;
                    p[0] = acc[jq][jc][4 * e4 + 0];
                    p[1] = acc[jq][jc][4 * e4 + 1];
                    p[2] = acc[jq][jc][4 * e4 + 2];
                    p[3] = acc[jq][jc][4 * e4 + 3];
                    *(f32x4*)(tb + 4 * (e4 ^ (l & 3))) = p;
                }
            }
    }
    __syncthreads();

    // ---- even waves (mh=0): combine + normalize + residual + store ----
    if (mh == 0) {
        const float* src = (const float*)(smem + ch * 32768);
        #pragma unroll
        for (int jq = 0; jq < 2; ++jq)
            #pragma unroll
            for (int jc = 0; jc < 4; ++jc) {
                const float* tb = src + (jq * 4 + jc) * 1024 + l * 16;
                #pragma unroll
                for (int e4 = 0; e4 < 4; ++e4) {
                    f32x4 p = *(const f32x4*)(tb + 4 * (e4 ^ (l & 3)));
                    acc[jq][jc][4 * e4 + 0] += p[0];
                    acc[jq][jc][4 * e4 + 1] += p[1];
                    acc[jq][jc][4 * e4 + 2] += p[2];
                    acc[jq][jc][4 * e4 + 3] += p[3];
                }
            }
        const float gm = gamma[0];
        #pragma unroll
        for (int jq = 0; jq < 2; ++jq)
            #pragma unroll
            for (int rg = 0; rg < 4; ++rg) {
                f32x4 s0 = *(const f32x4*)(rstab + (w * 2 + jq) * 32
                                           + 8 * rg + 4 * h2);
                f32x4 s1 = *(const f32x4*)(rstab + ((w + 1) * 2 + jq) * 32
                                           + 8 * rg + 4 * h2);
                float i0 = 1.0f / (s0[0] + s1[0]);
                float i1 = 1.0f / (s0[1] + s1[1]);
                float i2 = 1.0f / (s0[2] + s1[2]);
                float i3 = 1.0f / (s0[3] + s1[3]);
                const int n = n0 + 32 * jq + 8 * rg + 4 * h2;
                #pragma unroll
                for (int jc = 0; jc < 4; ++jc) {
                    const int c = 128 * ch + 32 * jc + l31;
                    const size_t rowoff = (size_t)(b * C_ + c) * N_ + n;
                    float4 xv = *(const float4*)(x + rowoff);
                    float4 o;
                    o.x = gm * acc[jq][jc][4 * rg + 0] * i0 + xv.x;
                    o.y = gm * acc[jq][jc][4 * rg + 1] * i1 + xv.y;
                    o.z = gm * acc[jq][jc][4 * rg + 2] * i2 + xv.z;
                    o.w = gm * acc[jq][jc][4 * rg + 3] * i3 + xv.w;
                    *(float4*)(out + rowoff) = o;
                }
            }
    }
}

// ---------------------------------------------------------------------------
extern "C" void kernel_launch(void* const* d_in, const int* in_sizes, int n_in,
                              void* d_out, int out_size, void* d_ws, size_t ws_size,
                              hipStream_t stream)
{
    const float* x     = (const float*)d_in[0];
    const float* Wq    = (const float*)d_in[1];
    const float* bq    = (const float*)d_in[2];
    const float* Wk    = (const float*)d_in[3];
    const float* bk    = (const float*)d_in[4];
    const float* Wv    = (const float*)d_in[5];
    const float* bv    = (const float*)d_in[6];
    const float* gamma = (const float*)d_in[7];
    float* out = (float*)d_out;

    ushort_t* ws = (ushort_t*)d_ws;
    ushort_t* Qb   = ws;                                  // B*N*32 bf16
    ushort_t* Kb   = Qb + (size_t)B_ * N_ * CQK_;         // B*N*32 bf16
    ushort_t* Vt   = Kb + (size_t)B_ * N_ * CQK_;         // B*64 chunks * 32KB
    ushort_t* Wall = Vt + (size_t)B_ * C_ * N_;           // 320*256 bf16
    float*    ball = (float*)(Wall + (size_t)320 * C_);   // 320 f32

    prep_kernel<<<320, 256, 0, stream>>>(Wq, bq, Wk, bk, Wv, bv, Wall, ball);
    proj_kernel<<<B_ * (N_ / 64), 256, 0, stream>>>(x, Wall, ball, Qb, Kb, Vt);
    attn_kernel<<<B_ * (N_ / 64), 256, 0, stream>>>(x, Qb, Kb, Vt, gamma, out);
}

// Round 13
// 130.510 us; speedup vs baseline: 1.4518x; 1.0572x over previous
//
#include <hip/hip_runtime.h>

static constexpr int B_   = 8;
static constexpr int C_   = 256;
static constexpr int CQK_ = 32;
static constexpr int N_   = 4096;   // 64*64

typedef __attribute__((ext_vector_type(4)))  float f32x4;
typedef __attribute__((ext_vector_type(16))) float f32x16;
typedef __attribute__((ext_vector_type(8)))  short short8;
typedef __attribute__((ext_vector_type(2)))  unsigned int u32x2;
typedef unsigned short ushort_t;

// round-to-nearest-even fp32 -> bf16
__device__ inline unsigned short f2bf(float f) {
    unsigned u = __float_as_uint(f);
    return (unsigned short)((u + 0x7FFFu + ((u >> 16) & 1u)) >> 16);
}
__device__ inline unsigned packbf(float lo, float hi) {
    return (unsigned)f2bf(lo) | ((unsigned)f2bf(hi) << 16);
}
// packed f32->bf16 pair, single VOP3 (validated r6+)
__device__ inline unsigned cvtpk(float lo, float hi) {
    unsigned r;
    asm("v_cvt_pk_bf16_f32 %0, %1, %2" : "=v"(r) : "v"(lo), "v"(hi));
    return r;
}
// raw transcendental exp2 (input = log2-domain; Q pre-scaled by log2e)
__device__ inline float vexp2(float x) {
    float r;
    asm("v_exp_f32 %0, %1" : "=v"(r) : "v"(x));
    return r;
}
// v_permlane32_swap_b32 (validated r10)
__device__ inline void plswap(unsigned& a, unsigned& b) {
    asm("v_permlane32_swap_b32 %0, %1" : "+v"(a), "+v"(b));
}

// proj x-tile swizzle (validated r3-r12)
__device__ inline int swzbits(int m) {
    return ((m & 3) << 5) | (((m >> 3) & 1) << 4);
}

template <int OFF>
__device__ inline u32x2 tr8(unsigned a) {
    u32x2 d;
    asm volatile("ds_read_b64_tr_b16 %0, %1 offset:%2"
                 : "=v"(d) : "v"(a), "i"(OFF));
    return d;
}

__device__ inline short8 mk8(u32x2 lo, u32x2 hi) {
    union { unsigned u[4]; short8 s; } v;
    v.u[0] = lo.x; v.u[1] = lo.y; v.u[2] = hi.x; v.u[3] = hi.y;
    return v.s;
}
__device__ inline short8 mk8u(unsigned a, unsigned b, unsigned c, unsigned d) {
    union { unsigned u[4]; short8 s; } v;
    v.u[0] = a; v.u[1] = b; v.u[2] = c; v.u[3] = d;
    return v.s;
}

// ---------------------------------------------------------------------------
// prep: weights -> bf16 (Wq pre-scaled by log2e), biases -> f32
// ---------------------------------------------------------------------------
__global__ __launch_bounds__(256) void prep_kernel(
    const float* __restrict__ Wq, const float* __restrict__ bq,
    const float* __restrict__ Wk, const float* __restrict__ bk,
    const float* __restrict__ Wv, const float* __restrict__ bv,
    ushort_t* __restrict__ Wall, float* __restrict__ ball)
{
    const int r = blockIdx.x;
    const int t = threadIdx.x;
    const float LOG2E = 1.4426950408889634f;
    const float* src;
    float bsrc, sc;
    if (r < 32)      { src = Wq + (size_t)r * C_;        bsrc = bq[r];      sc = LOG2E; }
    else if (r < 64) { src = Wk + (size_t)(r - 32) * C_; bsrc = bk[r - 32]; sc = 1.0f; }
    else             { src = Wv + (size_t)(r - 64) * C_; bsrc = bv[r - 64]; sc = 1.0f; }
    Wall[(size_t)r * C_ + t] = f2bf(src[t] * sc);
    if (t == 0) ball[r] = bsrc * sc;
}

// ---------------------------------------------------------------------------
// Projection via MFMA (r12-validated, incl. the V quadrant image:
//   byte = ((b*64+chunk)*4 + 2*ch + mh)*8192 + (c&127)*64
//        + 16*(((m&31)>>3) ^ (c&3) ^ ((c>>2)&3)) + 2*(m&7) )
// grid = 512 blocks (b = blk&7, XCD-affine), 256 threads (4 waves)
// ---------------------------------------------------------------------------
__global__ __launch_bounds__(256) void proj_kernel(
    const float* __restrict__ x,
    const ushort_t* __restrict__ Wall, const float* __restrict__ ball,
    ushort_t* __restrict__ Qb, ushort_t* __restrict__ Kb, ushort_t* __restrict__ Vt)
{
    __shared__ __align__(16) unsigned char xs[C_ * 128];   // 32 KB: [c][64n] bf16
    typedef __attribute__((address_space(3))) unsigned char lds_byte;
    const unsigned sbase = (unsigned)(size_t)(lds_byte*)xs;

    const int b  = blockIdx.x & 7;
    const int n0 = (blockIdx.x >> 3) << 6;
    const int t  = threadIdx.x;

    {
        const int cst = t >> 4;
        const int n4  = (t & 15) << 2;
        const float* xb = x + (size_t)b * C_ * N_ + n0;
        #pragma unroll
        for (int i = 0; i < 16; ++i) {
            const int c = 16 * i + cst;
            float4 v = *(const float4*)(xb + (size_t)c * N_ + n4);
            u32x2 pk;
            pk.x = packbf(v.x, v.y);
            pk.y = packbf(v.z, v.w);
            *(u32x2*)(xs + c * 128 + ((n4 * 2) ^ swzbits(c))) = pk;
        }
    }
    __syncthreads();

    const int l  = t & 63, w = t >> 6;
    const int li = l & 15, g = l >> 4;
    const int rr = li >> 2, ss = l & 3;
    const int swz_tr = (rr << 5) | ((g & 1) << 4);

    f32x4 acc[5][4];
    #pragma unroll
    for (int i = 0; i < 5; ++i)
        #pragma unroll
        for (int j = 0; j < 4; ++j) acc[i][j] = (f32x4){0.f, 0.f, 0.f, 0.f};

    #pragma unroll 2
    for (int kg = 0; kg < 8; ++kg) {
        u32x2 pb[4][2];
        #pragma unroll
        for (int jn = 0; jn < 4; ++jn) {
            unsigned a = sbase + (32 * kg + 8 * g + rr) * 128
                       + ((32 * jn + 8 * ss) ^ swz_tr);
            pb[jn][0] = tr8<0>(a);
            pb[jn][1] = tr8<512>(a);
        }
        short8 af[5];
        #pragma unroll
        for (int tm = 0; tm < 5; ++tm)
            af[tm] = *(const short8*)(Wall + (size_t)(16 * (4 * tm + w) + li) * C_
                                      + 32 * kg + 8 * g);
        asm volatile("s_waitcnt lgkmcnt(0)" ::: "memory");
        __builtin_amdgcn_sched_barrier(0);
        #pragma unroll
        for (int jn = 0; jn < 4; ++jn) {
            short8 Bf = mk8(pb[jn][0], pb[jn][1]);
            acc[0][jn] = __builtin_amdgcn_mfma_f32_16x16x32_bf16(
                             af[0], Bf, acc[0][jn], 0, 0, 0);
            #pragma unroll
            for (int tm = 1; tm < 5; ++tm)
                acc[tm][jn] = __builtin_amdgcn_mfma_f32_16x16x32_bf16(
                                  Bf, af[tm], acc[tm][jn], 0, 0, 0);
        }
    }

    // ---- epilogue: Q/K (unchanged, validated) ----
    {
        const int oc0 = 16 * w + 4 * g;
        float4 bias = *(const float4*)(ball + oc0);
        ushort_t* dst = (w < 2) ? Qb : Kb;
        const int col = (w < 2) ? oc0 : (oc0 - 32);
        #pragma unroll
        for (int jn = 0; jn < 4; ++jn) {
            const int n = n0 + 16 * jn + li;
            f32x4 a = acc[0][jn];
            u32x2 pk;
            pk.x = packbf(a[0] + bias.x, a[1] + bias.y);
            pk.y = packbf(a[2] + bias.z, a[3] + bias.w);
            *(u32x2*)(dst + (size_t)(b * N_ + n) * CQK_ + col) = pk;
        }
    }
    // ---- epilogue: V quadrant image (validated r12) ----
    #pragma unroll
    for (int tm = 1; tm < 5; ++tm) {
        const int c  = 16 * (4 * tm + w) + li - 64;
        const float bc = ball[64 + c];
        const int ch = c >> 7;
        const int cl = c & 127;
        const int X  = (c & 3) ^ ((c >> 2) & 3);
        char* qbase = (char*)Vt + ((size_t)(b * 64 + (n0 >> 6)) * 4 + 2 * ch) * 8192
                    + cl * 64;
        #pragma unroll
        for (int jn = 0; jn < 4; ++jn) {
            const int mp = 16 * jn + 4 * g;
            const int mh = mp >> 5;
            const int jg = (mp & 31) >> 3;
            f32x4 a = acc[tm][jn];
            u32x2 pk;
            pk.x = packbf(a[0] + bc, a[1] + bc);
            pk.y = packbf(a[2] + bc, a[3] + bc);
            *(u32x2*)(qbase + mh * 8192 + 16 * (jg ^ X) + 8 * (g & 1)) = pk;
        }
    }
}

// ---------------------------------------------------------------------------
// Fused attention: quadrant split + SOFTWARE-PIPELINED chunks:
// body n = { issue K(n+2), DMA(n+1); vmcnt(10); [PV(n) || QK(n+1)] }.
// P double-buffered in registers (pA/pB); setprio around compute.
// End: cross-wave combine of partial acc + rowsums (2 syncthreads).
// LDS: 4 waves * 2 * 8KB + 1KB rstab = 66560 B -> 2 blocks/CU.
// ---------------------------------------------------------------------------
__global__ __launch_bounds__(256, 2) void attn_kernel(
    const float* __restrict__ x,
    const ushort_t* __restrict__ Qb, const ushort_t* __restrict__ Kb,
    const ushort_t* __restrict__ Vt,
    const float* __restrict__ gamma, float* __restrict__ out)
{
    __shared__ __align__(16) unsigned char smem[66560];

    const int b   = blockIdx.x & 7;
    const int n0  = (blockIdx.x >> 3) << 6;
    const int t   = threadIdx.x;
    const int l   = t & 63, w = t >> 6;
    const int l31 = l & 31, h2 = l >> 5;
    const int mh  = w & 1,  ch = w >> 1;
    const int sxv = ((l31 & 3) ^ ((l31 >> 2) & 3)) << 4;
    unsigned char* wlds = smem + w * 16384;
    float* rstab = (float*)(smem + 65536);

    // Q fragments (B-role: col = l31 -> q = n0+32jq+l31; k = 16kh+8h2+j)
    short8 qfv[2][2];
    #pragma unroll
    for (int jq = 0; jq < 2; ++jq)
        #pragma unroll
        for (int kh = 0; kh < 2; ++kh)
            qfv[jq][kh] = *(const short8*)(Qb
                + (size_t)(b * N_ + n0 + 32 * jq + l31) * CQK_ + 16 * kh + 8 * h2);

    f32x16 acc[2][4];
    #pragma unroll
    for (int i = 0; i < 2; ++i)
        #pragma unroll
        for (int j = 0; j < 4; ++j)
            #pragma unroll
            for (int e = 0; e < 16; ++e) acc[i][j][e] = 0.f;
    f32x16 zf16;
    #pragma unroll
    for (int e = 0; e < 16; ++e) zf16[e] = 0.f;
    float rs[2] = {0.f, 0.f};

    const ushort_t* Kbb = Kb + (size_t)(b * N_) * CQK_;
    const char* Vgb = (const char*)Vt + (size_t)b * 64 * 32768
                    + (2 * ch + mh) * 8192;

    short8 kfA[2], kfB[2];
    unsigned pA[2][2][4], pB[2][2][4];

// QK for one jq of chunk using K-set KQ, exp2, pack+permlane into PN
#define QK_JQ(JQ, KQ, PN)                                                       \
    {                                                                           \
        f32x16 sv = __builtin_amdgcn_mfma_f32_32x32x16_bf16(                    \
                        KQ[0], qfv[JQ][0], zf16, 0, 0, 0);                      \
        sv = __builtin_amdgcn_mfma_f32_32x32x16_bf16(                           \
                 KQ[1], qfv[JQ][1], sv, 0, 0, 0);                               \
        _Pragma("unroll")                                                       \
        for (int s = 0; s < 2; ++s) {                                           \
            float e0 = vexp2(sv[8*s+0]), e1 = vexp2(sv[8*s+1]);                 \
            float e2 = vexp2(sv[8*s+2]), e3 = vexp2(sv[8*s+3]);                 \
            float e4 = vexp2(sv[8*s+4]), e5 = vexp2(sv[8*s+5]);                 \
            float e6 = vexp2(sv[8*s+6]), e7 = vexp2(sv[8*s+7]);                 \
            rs[JQ] += ((e0 + e1) + (e2 + e3)) + ((e4 + e5) + (e6 + e7));        \
            unsigned u0 = cvtpk(e0, e1), u1 = cvtpk(e2, e3);                    \
            unsigned u2 = cvtpk(e4, e5), u3 = cvtpk(e6, e7);                    \
            plswap(u0, u2); plswap(u1, u3);                                     \
            PN[JQ][s][0] = u0; PN[JQ][s][1] = u1;                               \
            PN[JQ][s][2] = u2; PN[JQ][s][3] = u3;                               \
        }                                                                       \
    }

// PV for one m-granule s of the chunk, A from PC, B from LDS buffer VB
#define PV_S(S, PC, VB)                                                         \
    {                                                                           \
        short8 A0 = mk8u(PC[0][S][0], PC[0][S][1], PC[0][S][2], PC[0][S][3]);   \
        short8 A1 = mk8u(PC[1][S][0], PC[1][S][1], PC[1][S][2], PC[1][S][3]);   \
        _Pragma("unroll")                                                       \
        for (int jc = 0; jc < 4; ++jc) {                                        \
            short8 vv = *(const short8*)((VB) + (32 * jc + l31) * 64            \
                           + ((32 * (S) + 16 * h2) ^ sxv));                     \
            acc[0][jc] = __builtin_amdgcn_mfma_f32_32x32x16_bf16(               \
                             A0, vv, acc[0][jc], 0, 0, 0);                      \
            acc[1][jc] = __builtin_amdgcn_mfma_f32_32x32x16_bf16(               \
                             A1, vv, acc[1][jc], 0, 0, 0);                      \
        }                                                                       \
    }

#define BODY(N, KQ, KL, PC, PN)                                                 \
    {                                                                           \
        const int chk = ((N) + 2) & 63;                                         \
        const int chd = ((N) + 1) & 63;                                         \
        /* 1. K(n+2) -> KL (set consumed by QK(n) last body) */                 \
        _Pragma("unroll")                                                       \
        for (int kh = 0; kh < 2; ++kh)                                          \
            KL[kh] = *(const short8*)(Kbb                                       \
                + (size_t)(64 * chk + 32 * mh + l31) * CQK_ + 16 * kh + 8 * h2);\
        /* 2. DMA(n+1) own quadrant -> other buffer */                          \
        {                                                                       \
            const char* gsrc = Vgb + (size_t)chd * 32768 + l * 16;              \
            unsigned char* ldst = wlds + (chd & 1) * 8192 + l * 16;             \
            _Pragma("unroll")                                                   \
            for (int i = 0; i < 8; ++i)                                         \
                __builtin_amdgcn_global_load_lds(                               \
                    (const __attribute__((address_space(1))) unsigned int*)(gsrc + i * 1024), \
                    (__attribute__((address_space(3))) unsigned int*)(ldst + i * 1024), \
                    16, 0, 0);                                                  \
        }                                                                       \
        /* 3. retire K(n+1)+DMA(n); keep K(n+2)+DMA(n+1)=10 in flight */        \
        asm volatile("s_waitcnt vmcnt(10)" ::: "memory");                       \
        /* 4. PV(n) || QK(n+1), staggered for latency hiding */                 \
        __builtin_amdgcn_s_setprio(1);                                          \
        {                                                                       \
            const unsigned char* vb = wlds + ((N) & 1) * 8192;                  \
            QK_JQ(0, KQ, PN)                                                    \
            PV_S(0, PC, vb)                                                     \
            QK_JQ(1, KQ, PN)                                                    \
            PV_S(1, PC, vb)                                                     \
        }                                                                       \
        __builtin_amdgcn_s_setprio(0);                                          \
    }

    // ---- prologue: K(0)->kfA, K(1)->kfB, DMA(0)->buf0, QK(0)->pA ----
    #pragma unroll
    for (int kh = 0; kh < 2; ++kh) {
        kfA[kh] = *(const short8*)(Kbb + (size_t)(32 * mh + l31) * CQK_
                                   + 16 * kh + 8 * h2);
        kfB[kh] = *(const short8*)(Kbb + (size_t)(64 + 32 * mh + l31) * CQK_
                                   + 16 * kh + 8 * h2);
    }
    #pragma unroll
    for (int i = 0; i < 8; ++i)
        __builtin_amdgcn_global_load_lds(
            (const __attribute__((address_space(1))) unsigned int*)(Vgb + l * 16 + i * 1024),
            (__attribute__((address_space(3))) unsigned int*)(wlds + l * 16 + i * 1024),
            16, 0, 0);
    asm volatile("s_waitcnt vmcnt(10)" ::: "memory");   // kfA retired
    QK_JQ(0, kfA, pA)
    QK_JQ(1, kfA, pA)

    for (int mc = 0; mc < 62; mc += 2) {
        BODY(mc,     kfB, kfA, pA, pB)
        BODY(mc + 1, kfA, kfB, pB, pA)
    }
    BODY(62, kfB, kfA, pA, pB)

    // ---- tail: PV(63) ----
    asm volatile("s_waitcnt vmcnt(0)" ::: "memory");
    {
        const unsigned char* vb = wlds + 8192;   // buf[63&1]
        PV_S(0, pB, vb)
        PV_S(1, pB, vb)
    }
#undef BODY
#undef PV_S
#undef QK_JQ

    // ---- partial rowsums (own m-half): combine h2 halves, publish ----
    #pragma unroll
    for (int jq = 0; jq < 2; ++jq)
        rs[jq] += __shfl_xor(rs[jq], 32, 64);
    if (l < 32) {
        rstab[(w * 2 + 0) * 32 + l31] = rs[0];
        rstab[(w * 2 + 1) * 32 + l31] = rs[1];
    }
    __syncthreads();

    // ---- odd waves (mh=1): write partial acc into V-buffer area ----
    if (mh == 1) {
        float* dst = (float*)(smem + ch * 32768);
        #pragma unroll
        for (int jq = 0; jq < 2; ++jq)
            #pragma unroll
            for (int jc = 0; jc < 4; ++jc) {
                float* tb = dst + (jq * 4 + jc) * 1024 + l * 16;
                #pragma unroll
                for (int e4 = 0; e4 < 4; ++e4) {
                    f32x4 p;
                    p[0] = acc[jq][jc][4 * e4 + 0];
                    p[1] = acc[jq][jc][4 * e4 + 1];
                    p[2] = acc[jq][jc][4 * e4 + 2];
                    p[3] = acc[jq][jc][4 * e4 + 3];
                    *(f32x4*)(tb + 4 * (e4 ^ (l & 3))) = p;
                }
            }
    }
    __syncthreads();

    // ---- even waves (mh=0): combine + normalize + residual + store ----
    if (mh == 0) {
        const float* src = (const float*)(smem + ch * 32768);
        #pragma unroll
        for (int jq = 0; jq < 2; ++jq)
            #pragma unroll
            for (int jc = 0; jc < 4; ++jc) {
                const float* tb = src + (jq * 4 + jc) * 1024 + l * 16;
                #pragma unroll
                for (int e4 = 0; e4 < 4; ++e4) {
                    f32x4 p = *(const f32x4*)(tb + 4 * (e4 ^ (l & 3)));
                    acc[jq][jc][4 * e4 + 0] += p[0];
                    acc[jq][jc][4 * e4 + 1] += p[1];
                    acc[jq][jc][4 * e4 + 2] += p[2];
                    acc[jq][jc][4 * e4 + 3] += p[3];
                }
            }
        const float gm = gamma[0];
        #pragma unroll
        for (int jq = 0; jq < 2; ++jq)
            #pragma unroll
            for (int rg = 0; rg < 4; ++rg) {
                f32x4 s0 = *(const f32x4*)(rstab + (w * 2 + jq) * 32
                                           + 8 * rg + 4 * h2);
                f32x4 s1 = *(const f32x4*)(rstab + ((w + 1) * 2 + jq) * 32
                                           + 8 * rg + 4 * h2);
                float i0 = 1.0f / (s0[0] + s1[0]);
                float i1 = 1.0f / (s0[1] + s1[1]);
                float i2 = 1.0f / (s0[2] + s1[2]);
                float i3 = 1.0f / (s0[3] + s1[3]);
                const int n = n0 + 32 * jq + 8 * rg + 4 * h2;
                #pragma unroll
                for (int jc = 0; jc < 4; ++jc) {
                    const int c = 128 * ch + 32 * jc + l31;
                    const size_t rowoff = (size_t)(b * C_ + c) * N_ + n;
                    float4 xv = *(const float4*)(x + rowoff);
                    float4 o;
                    o.x = gm * acc[jq][jc][4 * rg + 0] * i0 + xv.x;
                    o.y = gm * acc[jq][jc][4 * rg + 1] * i1 + xv.y;
                    o.z = gm * acc[jq][jc][4 * rg + 2] * i2 + xv.z;
                    o.w = gm * acc[jq][jc][4 * rg + 3] * i3 + xv.w;
                    *(float4*)(out + rowoff) = o;
                }
            }
    }
}

// ---------------------------------------------------------------------------
extern "C" void kernel_launch(void* const* d_in, const int* in_sizes, int n_in,
                              void* d_out, int out_size, void* d_ws, size_t ws_size,
                              hipStream_t stream)
{
    const float* x     = (const float*)d_in[0];
    const float* Wq    = (const float*)d_in[1];
    const float* bq    = (const float*)d_in[2];
    const float* Wk    = (const float*)d_in[3];
    const float* bk    = (const float*)d_in[4];
    const float* Wv    = (const float*)d_in[5];
    const float* bv    = (const float*)d_in[6];
    const float* gamma = (const float*)d_in[7];
    float* out = (float*)d_out;

    ushort_t* ws = (ushort_t*)d_ws;
    ushort_t* Qb   = ws;                                  // B*N*32 bf16
    ushort_t* Kb   = Qb + (size_t)B_ * N_ * CQK_;         // B*N*32 bf16
    ushort_t* Vt   = Kb + (size_t)B_ * N_ * CQK_;         // B*64 chunks * 32KB
    ushort_t* Wall = Vt + (size_t)B_ * C_ * N_;           // 320*256 bf16
    float*    ball = (float*)(Wall + (size_t)320 * C_);   // 320 f32

    prep_kernel<<<320, 256, 0, stream>>>(Wq, bq, Wk, bk, Wv, bv, Wall, ball);
    proj_kernel<<<B_ * (N_ / 64), 256, 0, stream>>>(x, Wall, ball, Qb, Kb, Vt);
    attn_kernel<<<B_ * (N_ / 64), 256, 0, stream>>>(x, Qb, Kb, Vt, gamma, out);
}